// Round 9
// baseline (227.659 us; speedup 1.0000x reference)
//
#include <hip/hip_runtime.h>
#include <hip/hip_bf16.h>
#include <hip/hip_cooperative_groups.h>

namespace cg = cooperative_groups;

#define BATCH     16384
#define INFEAT    4096
#define NCHUNK    8
#define CIN       512
#define COUT      512
#define OUT_MAIN  (BATCH * 1024)            // 16777216 f32 elements
#define NBLK      512
#define ROWS_PB   (BATCH / NBLK)            // 32 rows per block in phase A
#define LDA       40

typedef short bf16x8 __attribute__((ext_vector_type(8)));
typedef float f32x4  __attribute__((ext_vector_type(4)));

static __device__ inline unsigned short f2bf_rne(float f) {
    unsigned int u = __builtin_bit_cast(unsigned int, f);
    unsigned int r = (u + 0x7fffu + ((u >> 16) & 1u)) >> 16;
    return (unsigned short)r;
}

// ---------------- fused cooperative kernel: act -> topk -> wtrans -> gemm ----------------
union ShU {
    float sred[16];                                       // phase A
    struct { double sd[256]; double act8[8]; float actf[8]; int idx2[2]; } red;  // phase B
    float tile[32][33];                                   // phase C
    struct { unsigned short As[128 * LDA]; unsigned short Bs[128 * LDA]; } g;    // phase D
};

__global__ __launch_bounds__(256, 2)
void fused_all_kernel(const float* __restrict__ x, const float* __restrict__ W,
                      const float* __restrict__ bvec, float* __restrict__ out,
                      float* __restrict__ part, unsigned short* __restrict__ WT) {
    cg::grid_group grid = cg::this_grid();
    __shared__ __align__(16) ShU sh;

    int t = threadIdx.x;
    int bid = blockIdx.x;
    int lane = t & 63, wid = t >> 6;

    // ---------- Phase A: per-block partial abs-sums over 32 rows ----------
    {
        float acc[4] = {0.f, 0.f, 0.f, 0.f};
        int r0 = bid * ROWS_PB;
        for (int r = 0; r < ROWS_PB; ++r) {
            const float4* p = reinterpret_cast<const float4*>(x + (size_t)(r0 + r) * INFEAT);
#pragma unroll
            for (int c = 0; c < 4; ++c) {
                float4 v = p[c * 256 + t];
                acc[c] += fabsf(v.x) + fabsf(v.y) + fabsf(v.z) + fabsf(v.w);
            }
        }
#pragma unroll
        for (int c = 0; c < 4; ++c) {
            float v = acc[c];
            v += __shfl_xor(v, 32); v += __shfl_xor(v, 16); v += __shfl_xor(v, 8);
            v += __shfl_xor(v, 4);  v += __shfl_xor(v, 2);  v += __shfl_xor(v, 1);
            acc[c] = v;
        }
        if (lane == 0) {
#pragma unroll
            for (int c = 0; c < 4; ++c) sh.sred[wid * 4 + c] = acc[c];
        }
        __syncthreads();
        if (t < 8) {
            int c = t >> 1, hi = t & 1;
            part[bid * 8 + t] = sh.sred[(2 * hi) * 4 + c] + sh.sred[(2 * hi + 1) * 4 + c];
        }
    }

    grid.sync();   // part[] visible device-wide

    // ---------- Phase B: every block redundantly reduces part + topk ----------
    int i0r, i1r;
    {
        int k = t & 7, s = t >> 3;
        double a = 0.0;
        for (int i = s; i < NBLK; i += 32) a += (double)part[i * 8 + k];
        sh.red.sd[t] = a;
        __syncthreads();
        if (t < 8) {
            double tot = 0.0;
            for (int j = 0; j < 32; ++j) tot += sh.red.sd[j * 8 + t];
            double m = tot / ((double)BATCH * (double)CIN);
            sh.red.act8[t] = m;
            sh.red.actf[t] = (float)m;
        }
        __syncthreads();
        if (t == 0) {
            int i0 = 0;
            for (int i = 1; i < 8; ++i) if (sh.red.act8[i] > sh.red.act8[i0]) i0 = i;
            int i1 = -1;
            for (int i = 0; i < 8; ++i) {
                if (i == i0) continue;
                if (i1 < 0 || sh.red.act8[i] > sh.red.act8[i1]) i1 = i;
            }
            sh.red.idx2[0] = i0;
            sh.red.idx2[1] = i1;
        }
        if (bid == 0 && t < 8) out[OUT_MAIN + t] = sh.red.actf[t];
        __syncthreads();
        i0r = sh.red.idx2[0];
        i1r = sh.red.idx2[1];
        if (bid == 0 && t == 0) {
            out[OUT_MAIN + 8] = (float)i0r;
            out[OUT_MAIN + 9] = (float)i1r;
        }
        __syncthreads();   // LDS reuse safe
    }

    // ---------- Phase C: W transpose+convert; 512 blocks = 2 chunks x 256 tiles ----------
    {
        int c  = bid >> 8;            // 0..1
        int tl = bid & 255;           // 0..255
        int id = c ? i1r : i0r;
        int i0 = (tl & 15) * 32, o0 = (tl >> 4) * 32;
        int tx = t & 31, ty = t >> 5;
        const float* Wp = W + (size_t)id * (CIN * COUT);
#pragma unroll
        for (int r = 0; r < 4; ++r)
            sh.tile[ty + r * 8][tx] = Wp[(size_t)(i0 + ty + r * 8) * COUT + o0 + tx];
        __syncthreads();
        unsigned short* WTp = WT + (size_t)c * (CIN * COUT);
#pragma unroll
        for (int r = 0; r < 4; ++r)
            WTp[(size_t)(o0 + ty + r * 8) * CIN + i0 + tx] = f2bf_rne(sh.tile[tx][ty + r * 8]);
    }

    grid.sync();   // WT visible device-wide

    // ---------- Phase D: gemm, 2 jobs per block (c=0,1), 128x128 tile, BK=32 ----------
    {
        int bx = bid & 127, by = (bid >> 7) & 3;
        int brow = bx * 128, bnn = by * 128;
        int wm = wid >> 1, wn = wid & 1;
        int lrow = lane & 15, lgrp = lane >> 4;
        int sa_m = t >> 3, sa_c = t & 7;
        int sb_n = t >> 1, sb_h = (t & 1) * 16;

        for (int job = 0; job < 2; ++job) {
            int idxc = job ? i1r : i0r;
            const float* xbase = x + (size_t)brow * INFEAT + idxc * CIN;
            const unsigned short* wtbase = WT + (size_t)job * (CIN * COUT);

            f32x4 acc[4][4];
#pragma unroll
            for (int mi = 0; mi < 4; ++mi)
#pragma unroll
                for (int ni = 0; ni < 4; ++ni) acc[mi][ni] = (f32x4){0.f, 0.f, 0.f, 0.f};

            for (int kt = 0; kt < 16; ++kt) {
                int k0 = kt * 32;
                __syncthreads();
#pragma unroll
                for (int r = 0; r < 4; ++r) {
                    int m = r * 32 + sa_m;
                    float4 v = *reinterpret_cast<const float4*>(xbase + (size_t)m * INFEAT + k0 + sa_c * 4);
                    ushort4 sv;
                    sv.x = f2bf_rne(v.x); sv.y = f2bf_rne(v.y);
                    sv.z = f2bf_rne(v.z); sv.w = f2bf_rne(v.w);
                    *reinterpret_cast<ushort4*>(&sh.g.As[m * LDA + sa_c * 4]) = sv;
                }
                {
                    const unsigned short* bsrc = wtbase + (size_t)(bnn + sb_n) * CIN + k0 + sb_h;
                    uint4 b0 = *reinterpret_cast<const uint4*>(bsrc);
                    uint4 b1 = *reinterpret_cast<const uint4*>(bsrc + 8);
                    unsigned short* bdst = &sh.g.Bs[sb_n * LDA + sb_h];
                    *reinterpret_cast<uint4*>(bdst)     = b0;
                    *reinterpret_cast<uint4*>(bdst + 8) = b1;
                }
                __syncthreads();
                bf16x8 af[4], bfr[4];
#pragma unroll
                for (int mi = 0; mi < 4; ++mi)
                    af[mi] = *reinterpret_cast<const bf16x8*>(&sh.g.As[(wm * 64 + mi * 16 + lrow) * LDA + lgrp * 8]);
#pragma unroll
                for (int ni = 0; ni < 4; ++ni)
                    bfr[ni] = *reinterpret_cast<const bf16x8*>(&sh.g.Bs[(wn * 64 + ni * 16 + lrow) * LDA + lgrp * 8]);
#pragma unroll
                for (int mi = 0; mi < 4; ++mi)
#pragma unroll
                    for (int ni = 0; ni < 4; ++ni)
                        acc[mi][ni] = __builtin_amdgcn_mfma_f32_16x16x32_bf16(af[mi], bfr[ni], acc[mi][ni], 0, 0, 0);
            }

            float bias[4];
#pragma unroll
            for (int ni = 0; ni < 4; ++ni)
                bias[ni] = bvec[idxc * COUT + bnn + wn * 64 + ni * 16 + lrow];
#pragma unroll
            for (int mi = 0; mi < 4; ++mi) {
#pragma unroll
                for (int r = 0; r < 4; ++r) {
                    int row = brow + wm * 64 + mi * 16 + lgrp * 4 + r;
                    float* orow = out + (size_t)row * 1024 + job * 512 + bnn + wn * 64;
#pragma unroll
                    for (int ni = 0; ni < 4; ++ni)
                        orow[ni * 16 + lrow] = acc[mi][ni][r] + bias[ni];
                }
            }
        }
    }
}

// ================= fallback path (R4 structure, known-good) =================
__global__ __launch_bounds__(256, 4)
void act_partial_kernel(const float* __restrict__ x, float* __restrict__ part) {
    int t = threadIdx.x;
    float acc[4] = {0.f, 0.f, 0.f, 0.f};
    int r0 = blockIdx.x * 8;
    for (int r = 0; r < 8; ++r) {
        const float4* p = reinterpret_cast<const float4*>(x + (size_t)(r0 + r) * INFEAT);
#pragma unroll
        for (int c = 0; c < 4; ++c) {
            float4 v = p[c * 256 + t];
            acc[c] += fabsf(v.x) + fabsf(v.y) + fabsf(v.z) + fabsf(v.w);
        }
    }
#pragma unroll
    for (int c = 0; c < 4; ++c) {
        float v = acc[c];
        v += __shfl_xor(v, 32); v += __shfl_xor(v, 16); v += __shfl_xor(v, 8);
        v += __shfl_xor(v, 4);  v += __shfl_xor(v, 2);  v += __shfl_xor(v, 1);
        acc[c] = v;
    }
    __shared__ float sred[16];
    int wave = t >> 6, lane = t & 63;
    if (lane == 0) {
#pragma unroll
        for (int c = 0; c < 4; ++c) sred[wave * 4 + c] = acc[c];
    }
    __syncthreads();
    if (t < 8) {
        int c = t >> 1, hi = t & 1;
        part[blockIdx.x * 8 + t] = sred[(2 * hi) * 4 + c] + sred[(2 * hi + 1) * 4 + c];
    }
}

__global__ void finalize_topk_kernel(const float* __restrict__ part,
                                     float* __restrict__ out_act, float* __restrict__ out_idx,
                                     int* __restrict__ ws_idx) {
    int t = threadIdx.x;
    __shared__ double sd[256];
    __shared__ double act[8];
    int k = t & 7, s = t >> 3;
    double a = 0.0;
    for (int i = s; i < 2048; i += 32) a += (double)part[i * 8 + k];
    sd[t] = a;
    __syncthreads();
    if (t < 8) {
        double tot = 0.0;
        for (int j = 0; j < 32; ++j) tot += sd[t + 8 * j];
        double m = tot / ((double)BATCH * (double)CIN);
        act[t] = m;
        out_act[t] = (float)m;
    }
    __syncthreads();
    if (t == 0) {
        int i0 = 0;
        for (int i = 1; i < 8; ++i) if (act[i] > act[i0]) i0 = i;
        int i1 = -1;
        for (int i = 0; i < 8; ++i) {
            if (i == i0) continue;
            if (i1 < 0 || act[i] > act[i1]) i1 = i;
        }
        out_idx[0] = (float)i0; out_idx[1] = (float)i1;
        ws_idx[0] = i0; ws_idx[1] = i1;
    }
}

__global__ void wtrans_kernel(const float* __restrict__ W, const int* __restrict__ idx,
                              unsigned short* __restrict__ WT) {
    int c = blockIdx.z;
    int id = idx[c];
    __shared__ float tile[32][33];
    int tx = threadIdx.x, ty = threadIdx.y;
    const float* Wp = W + (size_t)id * (CIN * COUT);
    int i0 = blockIdx.x * 32, o0 = blockIdx.y * 32;
#pragma unroll
    for (int r = 0; r < 4; ++r)
        tile[ty + r * 8][tx] = Wp[(size_t)(i0 + ty + r * 8) * COUT + o0 + tx];
    __syncthreads();
    unsigned short* WTp = WT + (size_t)c * (CIN * COUT);
#pragma unroll
    for (int r = 0; r < 4; ++r)
        WTp[(size_t)(o0 + ty + r * 8) * CIN + i0 + tx] = f2bf_rne(tile[tx][ty + r * 8]);
}

__global__ __launch_bounds__(256, 2)
void gemm_topk_kernel(const float* __restrict__ x, const unsigned short* __restrict__ WT,
                      const float* __restrict__ bvec, const int* __restrict__ idxp,
                      float* __restrict__ out) {
    __shared__ __align__(16) unsigned short As[128 * LDA];
    __shared__ __align__(16) unsigned short Bs[128 * LDA];
    int c = blockIdx.z;
    int idx = idxp[c];
    int brow = blockIdx.x * 128, bn = blockIdx.y * 128;
    int t = threadIdx.x;
    int lane = t & 63, wid = t >> 6;
    int wm = wid >> 1, wn = wid & 1;
    int lrow = lane & 15, lgrp = lane >> 4;
    f32x4 acc[4][4] = {};
    const float* xbase = x + (size_t)brow * INFEAT + idx * CIN;
    const unsigned short* wtbase = WT + (size_t)c * (CIN * COUT);
    int sa_m = t >> 3, sa_c = t & 7;
    int sb_n = t >> 1, sb_h = (t & 1) * 16;
    for (int kt = 0; kt < 16; ++kt) {
        int k0 = kt * 32;
        __syncthreads();
#pragma unroll
        for (int r = 0; r < 4; ++r) {
            int m = r * 32 + sa_m;
            float4 v = *reinterpret_cast<const float4*>(xbase + (size_t)m * INFEAT + k0 + sa_c * 4);
            ushort4 sv;
            sv.x = f2bf_rne(v.x); sv.y = f2bf_rne(v.y); sv.z = f2bf_rne(v.z); sv.w = f2bf_rne(v.w);
            *reinterpret_cast<ushort4*>(&As[m * LDA + sa_c * 4]) = sv;
        }
        {
            const unsigned short* bsrc = wtbase + (size_t)(bn + sb_n) * CIN + k0 + sb_h;
            uint4 b0 = *reinterpret_cast<const uint4*>(bsrc);
            uint4 b1 = *reinterpret_cast<const uint4*>(bsrc + 8);
            unsigned short* bdst = &Bs[sb_n * LDA + sb_h];
            *reinterpret_cast<uint4*>(bdst) = b0;
            *reinterpret_cast<uint4*>(bdst + 8) = b1;
        }
        __syncthreads();
        bf16x8 af[4], bfr[4];
#pragma unroll
        for (int mi = 0; mi < 4; ++mi)
            af[mi] = *reinterpret_cast<const bf16x8*>(&As[(wm * 64 + mi * 16 + lrow) * LDA + lgrp * 8]);
#pragma unroll
        for (int ni = 0; ni < 4; ++ni)
            bfr[ni] = *reinterpret_cast<const bf16x8*>(&Bs[(wn * 64 + ni * 16 + lrow) * LDA + lgrp * 8]);
#pragma unroll
        for (int mi = 0; mi < 4; ++mi)
#pragma unroll
            for (int ni = 0; ni < 4; ++ni)
                acc[mi][ni] = __builtin_amdgcn_mfma_f32_16x16x32_bf16(af[mi], bfr[ni], acc[mi][ni], 0, 0, 0);
    }
    float bias[4];
#pragma unroll
    for (int ni = 0; ni < 4; ++ni)
        bias[ni] = bvec[idx * COUT + bn + wn * 64 + ni * 16 + lrow];
#pragma unroll
    for (int mi = 0; mi < 4; ++mi) {
#pragma unroll
        for (int r = 0; r < 4; ++r) {
            int row = brow + wm * 64 + mi * 16 + lgrp * 4 + r;
            float* orow = out + (size_t)row * 1024 + c * 512 + bn + wn * 64;
#pragma unroll
            for (int ni = 0; ni < 4; ++ni)
                orow[ni * 16 + lrow] = acc[mi][ni][r] + bias[ni];
        }
    }
}

extern "C" void kernel_launch(void* const* d_in, const int* in_sizes, int n_in,
                              void* d_out, int out_size, void* d_ws, size_t ws_size,
                              hipStream_t stream) {
    const float* x = (const float*)d_in[0];
    const float* W = (const float*)d_in[1];
    const float* bv = (const float*)d_in[2];
    float* out = (float*)d_out;

    float* part = (float*)d_ws;                               // 16 KB used (coop) / 64 KB (fallback)
    int* ws_idx = (int*)((char*)d_ws + 65536);
    unsigned short* WT = (unsigned short*)((char*)d_ws + 65792);

    void* args[] = {(void*)&x, (void*)&W, (void*)&bv, (void*)&out, (void*)&part, (void*)&WT};
    hipError_t e = hipLaunchCooperativeKernel((const void*)fused_all_kernel,
                                              dim3(NBLK), dim3(256), args, 0, stream);
    if (e != hipSuccess) {
        // fallback: known-good R4 4-kernel path
        act_partial_kernel<<<2048, 256, 0, stream>>>(x, part);
        finalize_topk_kernel<<<1, 256, 0, stream>>>(part, out + OUT_MAIN, out + OUT_MAIN + 8, ws_idx);
        wtrans_kernel<<<dim3(16, 16, 2), dim3(32, 8), 0, stream>>>(W, ws_idx, WT);
        gemm_topk_kernel<<<dim3(BATCH / 128, COUT / 128, 2), 256, 0, stream>>>(x, WT, bv, ws_idx, out);
    }
}

// Round 10
// 105.577 us; speedup vs baseline: 2.1563x; 2.1563x over previous
//
#include <hip/hip_runtime.h>
#include <hip/hip_bf16.h>

#define BATCH     16384
#define INFEAT    4096
#define NCHUNK    8
#define CIN       512
#define COUT      512
#define ACT_GRID  2048
#define OUT_MAIN  (BATCH * 1024)            // 16777216 f32 elements
#define LDA       40

typedef short bf16x8 __attribute__((ext_vector_type(8)));
typedef float f32x4  __attribute__((ext_vector_type(4)));

static __device__ inline unsigned short f2bf_rne(float f) {
    unsigned int u = __builtin_bit_cast(unsigned int, f);
    unsigned int r = (u + 0x7fffu + ((u >> 16) & 1u)) >> 16;
    return (unsigned short)r;
}

// ---------------- K1: per-block partial abs-sums; part is chunk-major [8][2048] ----------------
__global__ __launch_bounds__(256, 4)
void act_partial_kernel(const float* __restrict__ x, float* __restrict__ part) {
    int t = threadIdx.x;
    float acc[4] = {0.f, 0.f, 0.f, 0.f};
    int r0 = blockIdx.x * 8;
    for (int r = 0; r < 8; ++r) {
        const float4* p = reinterpret_cast<const float4*>(x + (size_t)(r0 + r) * INFEAT);
#pragma unroll
        for (int c = 0; c < 4; ++c) {
            float4 v = p[c * 256 + t];
            acc[c] += fabsf(v.x) + fabsf(v.y) + fabsf(v.z) + fabsf(v.w);
        }
    }
#pragma unroll
    for (int c = 0; c < 4; ++c) {
        float v = acc[c];
        v += __shfl_xor(v, 32); v += __shfl_xor(v, 16); v += __shfl_xor(v, 8);
        v += __shfl_xor(v, 4);  v += __shfl_xor(v, 2);  v += __shfl_xor(v, 1);
        acc[c] = v;
    }
    __shared__ float sred[16];
    int wave = t >> 6, lane = t & 63;
    if (lane == 0) {
#pragma unroll
        for (int c = 0; c < 4; ++c) sred[wave * 4 + c] = acc[c];
    }
    __syncthreads();
    if (t < 8) {
        int c = t >> 1, hi = t & 1;
        // chunk-major: part[chunk][block]
        part[t * ACT_GRID + blockIdx.x] = sred[(2 * hi) * 4 + c] + sred[(2 * hi + 1) * 4 + c];
    }
}

// Redundant per-block topk from part. Fixed summation order -> bit-identical result in
// every block of every kernel. Returns via sidx[2]/act8[8] in shared.
// Requires 256 threads, a 2KB f64 scratch, and two small shared arrays.
template <typename ShD>
static __device__ inline void topk_preamble(const float* __restrict__ part, int tt,
                                            ShD* sd, double* act8, int* sidx) {
    int ch = tt >> 5, g = tt & 31;
    double a = 0.0;
    for (int j = 0; j < 64; ++j) a += (double)part[ch * ACT_GRID + g + 32 * j];
    sd[tt] = a;
    __syncthreads();
    if (tt < 8) {
        double tot = 0.0;
        for (int j = 0; j < 32; ++j) tot += sd[tt * 32 + j];
        act8[tt] = tot;
    }
    __syncthreads();
    if (tt == 0) {
        int i0 = 0;
        for (int i = 1; i < 8; ++i) if (act8[i] > act8[i0]) i0 = i;
        int i1 = -1;
        for (int i = 0; i < 8; ++i) {
            if (i == i0) continue;
            if (i1 < 0 || act8[i] > act8[i1]) i1 = i;
        }
        sidx[0] = i0; sidx[1] = i1;
    }
    __syncthreads();
}

// ---------------- K2: topk + W transpose/convert; block (0,0,0) writes act/idx outputs ----------------
__global__ void wtrans_topk_kernel(const float* __restrict__ W, const float* __restrict__ part,
                                   float* __restrict__ out, unsigned short* __restrict__ WT) {
    __shared__ union { double sd[256]; float tile[32][33]; } sh;
    __shared__ double act8[8];
    __shared__ int sidx[2];
    int tx = threadIdx.x, ty = threadIdx.y;
    int tt = ty * 32 + tx;

    topk_preamble(part, tt, sh.sd, act8, sidx);

    int c = blockIdx.z;
    int id = sidx[c];
    if (blockIdx.x == 0 && blockIdx.y == 0 && c == 0) {
        if (tt < 8) out[OUT_MAIN + tt] = (float)(act8[tt] / ((double)BATCH * (double)CIN));
        if (tt == 0) {
            out[OUT_MAIN + 8] = (float)sidx[0];
            out[OUT_MAIN + 9] = (float)sidx[1];
        }
    }
    __syncthreads();   // sd reads complete before tile reuse

    const float* Wp = W + (size_t)id * (CIN * COUT);
    int i0 = blockIdx.x * 32, o0 = blockIdx.y * 32;
#pragma unroll
    for (int r = 0; r < 4; ++r)
        sh.tile[ty + r * 8][tx] = Wp[(size_t)(i0 + ty + r * 8) * COUT + o0 + tx];
    __syncthreads();
    unsigned short* WTp = WT + (size_t)c * (CIN * COUT);
#pragma unroll
    for (int r = 0; r < 4; ++r)
        WTp[(size_t)(o0 + ty + r * 8) * CIN + i0 + tx] = f2bf_rne(sh.tile[tx][ty + r * 8]);
}

// ---------------- K3: topk + GEMM (R4 structure verbatim), 128x128, BK=32 ----------------
__global__ __launch_bounds__(256, 2)
void gemm_topk_kernel(const float* __restrict__ x, const unsigned short* __restrict__ WT,
                      const float* __restrict__ bvec, const float* __restrict__ part,
                      float* __restrict__ out) {
    __shared__ union {
        double sd[256];
        struct { unsigned short As[128 * LDA]; unsigned short Bs[128 * LDA]; } g;
    } sh;
    __shared__ double act8[8];
    __shared__ int sidx[2];
    int t = threadIdx.x;

    topk_preamble(part, t, sh.sd, act8, sidx);

    int c = blockIdx.z;
    int idx = sidx[c];
    __syncthreads();   // everyone has idx in-register path; sd free for As/Bs reuse

    int brow = blockIdx.x * 128, bn = blockIdx.y * 128;
    int lane = t & 63, wid = t >> 6;
    int wm = wid >> 1, wn = wid & 1;
    int lrow = lane & 15, lgrp = lane >> 4;
    f32x4 acc[4][4] = {};
    const float* xbase = x + (size_t)brow * INFEAT + idx * CIN;
    const unsigned short* wtbase = WT + (size_t)c * (CIN * COUT);
    int sa_m = t >> 3, sa_c = t & 7;
    int sb_n = t >> 1, sb_h = (t & 1) * 16;

    for (int kt = 0; kt < 16; ++kt) {
        int k0 = kt * 32;
        __syncthreads();
#pragma unroll
        for (int r = 0; r < 4; ++r) {
            int m = r * 32 + sa_m;
            float4 v = *reinterpret_cast<const float4*>(xbase + (size_t)m * INFEAT + k0 + sa_c * 4);
            ushort4 sv;
            sv.x = f2bf_rne(v.x); sv.y = f2bf_rne(v.y); sv.z = f2bf_rne(v.z); sv.w = f2bf_rne(v.w);
            *reinterpret_cast<ushort4*>(&sh.g.As[m * LDA + sa_c * 4]) = sv;
        }
        {
            const unsigned short* bsrc = wtbase + (size_t)(bn + sb_n) * CIN + k0 + sb_h;
            uint4 b0 = *reinterpret_cast<const uint4*>(bsrc);
            uint4 b1 = *reinterpret_cast<const uint4*>(bsrc + 8);
            unsigned short* bdst = &sh.g.Bs[sb_n * LDA + sb_h];
            *reinterpret_cast<uint4*>(bdst)     = b0;
            *reinterpret_cast<uint4*>(bdst + 8) = b1;
        }
        __syncthreads();
        bf16x8 af[4], bfr[4];
#pragma unroll
        for (int mi = 0; mi < 4; ++mi)
            af[mi] = *reinterpret_cast<const bf16x8*>(&sh.g.As[(wm * 64 + mi * 16 + lrow) * LDA + lgrp * 8]);
#pragma unroll
        for (int ni = 0; ni < 4; ++ni)
            bfr[ni] = *reinterpret_cast<const bf16x8*>(&sh.g.Bs[(wn * 64 + ni * 16 + lrow) * LDA + lgrp * 8]);
#pragma unroll
        for (int mi = 0; mi < 4; ++mi)
#pragma unroll
            for (int ni = 0; ni < 4; ++ni)
                acc[mi][ni] = __builtin_amdgcn_mfma_f32_16x16x32_bf16(af[mi], bfr[ni], acc[mi][ni], 0, 0, 0);
    }

    float bias[4];
#pragma unroll
    for (int ni = 0; ni < 4; ++ni)
        bias[ni] = bvec[idx * COUT + bn + wn * 64 + ni * 16 + lrow];
#pragma unroll
    for (int mi = 0; mi < 4; ++mi) {
#pragma unroll
        for (int r = 0; r < 4; ++r) {
            int row = brow + wm * 64 + mi * 16 + lgrp * 4 + r;
            float* orow = out + (size_t)row * 1024 + c * 512 + bn + wn * 64;
#pragma unroll
            for (int ni = 0; ni < 4; ++ni)
                orow[ni * 16 + lrow] = acc[mi][ni][r] + bias[ni];
        }
    }
}

extern "C" void kernel_launch(void* const* d_in, const int* in_sizes, int n_in,
                              void* d_out, int out_size, void* d_ws, size_t ws_size,
                              hipStream_t stream) {
    const float* x = (const float*)d_in[0];
    const float* W = (const float*)d_in[1];
    const float* bv = (const float*)d_in[2];
    float* out = (float*)d_out;

    float* part = (float*)d_ws;                                    // 64 KB, chunk-major [8][2048]
    unsigned short* WT = (unsigned short*)((char*)d_ws + 65792);   // 2 MB bf16 n-major

    act_partial_kernel<<<ACT_GRID, 256, 0, stream>>>(x, part);
    wtrans_topk_kernel<<<dim3(16, 16, 2), dim3(32, 8), 0, stream>>>(W, part, out, WT);
    gemm_topk_kernel<<<dim3(BATCH / 128, COUT / 128, 2), 256, 0, stream>>>(x, WT, bv, part, out);
}